// Round 9
// baseline (1007.266 us; speedup 1.0000x reference)
//
#include <hip/hip_runtime.h>
#include <hip/hip_bf16.h>

typedef unsigned short ushort_t;
typedef __attribute__((ext_vector_type(8))) short short8;
typedef __attribute__((ext_vector_type(4))) short short4v;
typedef __attribute__((ext_vector_type(4))) float floatx4;

#define MFMA16(a, b, c) __builtin_amdgcn_mfma_f32_16x16x32_bf16(a, b, c, 0, 0, 0)

#if __has_builtin(__builtin_amdgcn_mfma_f32_16x16x16bf16_1k)
#define MFMA16K16(a, b, c) __builtin_amdgcn_mfma_f32_16x16x16bf16_1k(a, b, c, 0, 0, 0)
#else
static __device__ __forceinline__ floatx4 mfma_bf16_k16(short4v a, short4v b, floatx4 c) {
    floatx4 d;
    asm volatile("s_nop 2\n\tv_mfma_f32_16x16x16_bf16 %0, %1, %2, %3"
                 : "=v"(d)
                 : "v"(a), "v"(b), "v"(c));
    return d;
}
#define MFMA16K16(a, b, c) mfma_bf16_k16(a, b, c)
#endif

__device__ __forceinline__ float bf2f(ushort_t u) {
    unsigned int v = ((unsigned int)u) << 16;
    return __int_as_float((int)v);
}
__device__ __forceinline__ ushort_t f2bf(float f) {
    unsigned int x = (unsigned int)__float_as_int(f);
    unsigned int r = (x + 0x7FFFu + ((x >> 16) & 1u)) >> 16;
    return (ushort_t)r;
}

// ---------------------------------------------------------------- fp32 -> bf16 convert
__global__ __launch_bounds__(256) void k_cvt(const floatx4* __restrict__ src,
                                             short4v* __restrict__ dst, int n4) {
    int i = blockIdx.x * 256 + threadIdx.x;
    if (i < n4) {
        floatx4 v = src[i];
        short4v o;
        o[0] = (short)f2bf(v[0]);
        o[1] = (short)f2bf(v[1]);
        o[2] = (short)f2bf(v[2]);
        o[3] = (short)f2bf(v[3]);
        dst[i] = o;
    }
}

// ---------------------------------------------------------------- fp32 transpose -> bf16
__global__ __launch_bounds__(256) void k_transpose_cvt(const float* __restrict__ src,
                                                       ushort_t* __restrict__ dst, int R, int C) {
    __shared__ float t[32][33];
    int tx = threadIdx.x & 31, ty = threadIdx.x >> 5;
    int r0 = blockIdx.y * 32, c0 = blockIdx.x * 32;
    for (int y = ty; y < 32; y += 8) t[y][tx] = src[(r0 + y) * C + c0 + tx];
    __syncthreads();
    for (int y = ty; y < 32; y += 8) dst[(c0 + y) * R + r0 + tx] = f2bf(t[tx][y]);
}

// ---------------------------------------------------------------- K1: qkv = x @ w_qkv
__global__ __launch_bounds__(256, 3) void k_qkv(const ushort_t* __restrict__ x,
                                                const ushort_t* __restrict__ wt,
                                                ushort_t* __restrict__ qs,
                                                ushort_t* __restrict__ ks,
                                                ushort_t* __restrict__ vt) {
    __shared__ __align__(16) ushort_t st[9216];  // 128*72 (q/k) or 64*136 (vT)
    const int tid = threadIdx.x, lane = tid & 63, wv = tid >> 6;
    const int col = lane & 15, quad = lane >> 4;
    const int which = blockIdx.x >> 3, hh = blockIdx.x & 7;
    const int c0 = blockIdx.x * 64;
    const int absrow0 = blockIdx.y * 128;
    const int bb = blockIdx.y >> 4, n0 = (blockIdx.y & 15) * 128;
    const int hidx = bb * 8 + hh;
    const int row0 = absrow0 + wv * 32;
    floatx4 acc[2][4];
#pragma unroll
    for (int i = 0; i < 2; i++)
#pragma unroll
        for (int j = 0; j < 4; j++) acc[i][j] = (floatx4){0.f, 0.f, 0.f, 0.f};
    for (int k0 = 0; k0 < 512; k0 += 32) {
        const int ko = k0 + quad * 8;
        short8 a0 = *(const short8*)&x[(row0 + col) * 512 + ko];
        short8 a1 = *(const short8*)&x[(row0 + 16 + col) * 512 + ko];
        short8 b0 = *(const short8*)&wt[(c0 + col) * 512 + ko];
        short8 b1 = *(const short8*)&wt[(c0 + 16 + col) * 512 + ko];
        short8 b2 = *(const short8*)&wt[(c0 + 32 + col) * 512 + ko];
        short8 b3 = *(const short8*)&wt[(c0 + 48 + col) * 512 + ko];
        acc[0][0] = MFMA16(a0, b0, acc[0][0]);
        acc[0][1] = MFMA16(a0, b1, acc[0][1]);
        acc[0][2] = MFMA16(a0, b2, acc[0][2]);
        acc[0][3] = MFMA16(a0, b3, acc[0][3]);
        acc[1][0] = MFMA16(a1, b0, acc[1][0]);
        acc[1][1] = MFMA16(a1, b1, acc[1][1]);
        acc[1][2] = MFMA16(a1, b2, acc[1][2]);
        acc[1][3] = MFMA16(a1, b3, acc[1][3]);
    }
    const float qscale = (which == 0) ? 0.125f : 1.0f;  // fold SCALE into q
#pragma unroll
    for (int i = 0; i < 2; i++)
#pragma unroll
        for (int j = 0; j < 4; j++)
#pragma unroll
            for (int r = 0; r < 4; r++) {
                int il = wv * 32 + i * 16 + quad * 4 + r;  // 0..127
                int cl = j * 16 + col;                     // 0..63
                ushort_t hv = f2bf(acc[i][j][r] * qscale);
                if (which == 2) st[cl * 136 + il] = hv;  // transposed: [d][n]
                else            st[il * 72 + cl] = hv;   // [n][d]
            }
    __syncthreads();
    if (which < 2) {
        ushort_t* dst = (which == 0) ? qs : ks;
#pragma unroll
        for (int s = tid; s < 1024; s += 256) {
            int rr = s >> 3, dc = (s & 7) * 8;
            *(short8*)&dst[(hidx * 2048 + n0 + rr) * 64 + dc] = *(const short8*)&st[rr * 72 + dc];
        }
    } else {
#pragma unroll
        for (int s = tid; s < 1024; s += 256) {
            int d = s >> 4, nc = (s & 15) * 8;
            *(short8*)&vt[(hidx * 64 + d) * 2048 + n0 + nc] = *(const short8*)&st[d * 136 + nc];
        }
    }
}

// ---------------------------------------------------------------- K2: barrier-free attention
// Block = (b, 16 q-rows), 4 waves, 1 wave/SIMD (512-reg budget). Wave owns j-span
// [wv*512, wv*512+512). Computes S^T = MFMA(A=K, B=Q) so the C-layout of exp output
// IS the A-operand layout for 16x16x16 PV MFMA — no LDS transpose, no in-loop barriers.
// Phase 1: l_g (barrier-free). Reduce. Phase 2: recompute S^T, premix+exp*linv+postmix
// in registers (weights VGPR-resident), PV per e. Epilogue: cross-wave reduce + proj.
__global__ __launch_bounds__(256, 1) void k_attn(const ushort_t* __restrict__ qs,
                                                 const ushort_t* __restrict__ ks,
                                                 const ushort_t* __restrict__ vt,
                                                 const float* __restrict__ w_pre,
                                                 const float* __restrict__ w_post,
                                                 const ushort_t* __restrict__ wot,
                                                 const float* __restrict__ bias,
                                                 float* __restrict__ out) {
    __shared__ float wlds[128];
    __shared__ float lred[4][8][16];
    __shared__ float linv_l[8][16];
    __shared__ float slotf[4 * 16 * 68];                  // 17.4 KB
    __shared__ __align__(16) ushort_t oline[16 * 520];    // 16.6 KB
    const int tid = threadIdx.x, lane = tid & 63, wv = tid >> 6;
    const int col = lane & 15, quad = lane >> 4;
    const int b = blockIdx.y, n0 = blockIdx.x * 16;

    if (tid < 128) wlds[tid] = (tid < 64) ? w_pre[tid] : w_post[tid - 64];
    __syncthreads();
    float wp[64], wq[64];
#pragma unroll
    for (int i = 0; i < 64; i++) { wp[i] = wlds[i]; wq[i] = wlds[64 + i]; }

    // register-cached Q fragments (B-operand: lane holds Q[i=col][d=quad*8..+8])
    short8 Qf[8][2];
#pragma unroll
    for (int h = 0; h < 8; h++) {
        const ushort_t* qb = &qs[((b * 8 + h) * 2048 + n0 + col) * 64 + quad * 8];
        Qf[h][0] = *(const short8*)&qb[0];
        Qf[h][1] = *(const short8*)&qb[32];
    }

    // ================= phase 1: l_g over this wave's 512-j span (no barriers)
    float Lacc[8];
#pragma unroll
    for (int g = 0; g < 8; g++) Lacc[g] = 0.f;
    for (int st = 0; st < 32; st++) {
        const int jw = wv * 512 + st * 16;
        floatx4 P2[8];
#pragma unroll
        for (int g = 0; g < 8; g++) P2[g] = (floatx4){0.f, 0.f, 0.f, 0.f};
#pragma unroll
        for (int h = 0; h < 8; h++) {
            const ushort_t* kb = &ks[((b * 8 + h) * 2048 + jw + col) * 64 + quad * 8];
            short8 k0 = *(const short8*)&kb[0];
            short8 k1 = *(const short8*)&kb[32];
            floatx4 sh = (floatx4){0.f, 0.f, 0.f, 0.f};
            sh = MFMA16(k0, Qf[h][0], sh);  // A=K, B=Q -> S^T
            sh = MFMA16(k1, Qf[h][1], sh);
#pragma unroll
            for (int g = 0; g < 8; g++) P2[g] += sh * wp[g * 8 + h];
        }
#pragma unroll
        for (int g = 0; g < 8; g++) {
            floatx4 p = P2[g];
            Lacc[g] += __expf(p[0]) + __expf(p[1]) + __expf(p[2]) + __expf(p[3]);
        }
    }
#pragma unroll
    for (int g = 0; g < 8; g++) {
        float v = Lacc[g];
        v += __shfl_xor(v, 16, 64);
        v += __shfl_xor(v, 32, 64);
        if (lane < 16) lred[wv][g][lane] = v;
    }
    __syncthreads();
    if (tid < 128) {
        int g = tid >> 4, ii = tid & 15;
        float l = lred[0][g][ii] + lred[1][g][ii] + lred[2][g][ii] + lred[3][g][ii];
        linv_l[g][ii] = 1.0f / l;
    }
    __syncthreads();
    float linvr[8];
#pragma unroll
    for (int g = 0; g < 8; g++) linvr[g] = linv_l[g][col];  // i == col in S^T layout

    // ================= phase 2: recompute, mix, PV (no barriers)
    floatx4 O[8][4];  // [e][nt]
#pragma unroll
    for (int e = 0; e < 8; e++)
#pragma unroll
        for (int nt = 0; nt < 4; nt++) O[e][nt] = (floatx4){0.f, 0.f, 0.f, 0.f};

    for (int st = 0; st < 32; st++) {
        const int jw = wv * 512 + st * 16;
        floatx4 P2[8];
#pragma unroll
        for (int g = 0; g < 8; g++) P2[g] = (floatx4){0.f, 0.f, 0.f, 0.f};
#pragma unroll
        for (int h = 0; h < 8; h++) {
            const ushort_t* kb = &ks[((b * 8 + h) * 2048 + jw + col) * 64 + quad * 8];
            short8 k0 = *(const short8*)&kb[0];
            short8 k1 = *(const short8*)&kb[32];
            floatx4 sh = (floatx4){0.f, 0.f, 0.f, 0.f};
            sh = MFMA16(k0, Qf[h][0], sh);
            sh = MFMA16(k1, Qf[h][1], sh);
#pragma unroll
            for (int g = 0; g < 8; g++) P2[g] += sh * wp[g * 8 + h];
        }
        // normalized exp
        float Un[8][4];
#pragma unroll
        for (int g = 0; g < 8; g++)
#pragma unroll
            for (int r = 0; r < 4; r++) Un[g][r] = __expf(P2[g][r]) * linvr[g];
        // postmix -> A-fragments (value(quad,col,r) = P_hat[i=col][j=jw+quad*4+r])
        short4v Af[8];
#pragma unroll
        for (int e = 0; e < 8; e++) {
#pragma unroll
            for (int r = 0; r < 4; r++) {
                float a = 0.f;
#pragma unroll
                for (int g = 0; g < 8; g++) a = fmaf(wq[e * 8 + g], Un[g][r], a);
                Af[e][r] = (short)f2bf(a);
            }
        }
        // PV: O[e][nt] += P_hat_e (K=16) @ V_e[j, d]
#pragma unroll
        for (int e = 0; e < 8; e++) {
            const ushort_t* vb = &vt[((b * 8 + e) * 64 + col) * 2048 + jw + quad * 4];
#pragma unroll
            for (int nt = 0; nt < 4; nt++) {
                short4v bf = *(const short4v*)&vb[nt * 16 * 2048];
                O[e][nt] = MFMA16K16(Af[e], bf, O[e][nt]);
            }
        }
    }

    // ================= epilogue: e-staged cross-wave O reduce -> oline
#pragma unroll 1
    for (int e = 0; e < 8; e++) {
#pragma unroll
        for (int nt = 0; nt < 4; nt++)
#pragma unroll
            for (int r = 0; r < 4; r++)
                slotf[wv * 1088 + (quad * 4 + r) * 68 + nt * 16 + col] = O[e][nt][r];
        __syncthreads();
        {
            int i = tid >> 4, d0 = (tid & 15) * 4;
#pragma unroll
            for (int k = 0; k < 4; k++) {
                int d = d0 + k;
                float s = slotf[0 * 1088 + i * 68 + d] + slotf[1 * 1088 + i * 68 + d] +
                          slotf[2 * 1088 + i * 68 + d] + slotf[3 * 1088 + i * 68 + d];
                oline[i * 520 + e * 64 + d] = f2bf(s);
            }
        }
        __syncthreads();
    }
    // ---- fused output projection: out[16 x 512] = oline @ w_out + bias
#pragma unroll
    for (int ct = 0; ct < 8; ct++) {
        floatx4 acc = (floatx4){0.f, 0.f, 0.f, 0.f};
        const int c = wv * 128 + ct * 16 + col;
#pragma unroll
        for (int k2 = 0; k2 < 16; k2++) {
            short8 af = *(const short8*)&oline[col * 520 + k2 * 32 + quad * 8];
            short8 bf = *(const short8*)&wot[c * 512 + k2 * 32 + quad * 8];
            acc = MFMA16(af, bf, acc);
        }
        float bz = bias[c];
#pragma unroll
        for (int r = 0; r < 4; r++)
            out[(b * 2048 + n0 + quad * 4 + r) * 512 + c] = acc[r] + bz;
    }
}

// ---------------------------------------------------------------- launch
extern "C" void kernel_launch(void* const* d_in, const int* in_sizes, int n_in,
                              void* d_out, int out_size, void* d_ws, size_t ws_size,
                              hipStream_t stream) {
    const float* x = (const float*)d_in[0];
    const float* w_qkv = (const float*)d_in[1];
    const float* w_pre = (const float*)d_in[2];
    const float* w_post = (const float*)d_in[3];
    const float* w_out = (const float*)d_in[4];
    const float* b_out = (const float*)d_in[5];
    char* ws = (char*)d_ws;
    ushort_t* qs = (ushort_t*)(ws);                            // 4 MB  [b,h,n,d] (pre-scaled)
    ushort_t* ks = (ushort_t*)(ws + (4u << 20));               // 4 MB  [b,h,n,d]
    ushort_t* vt = (ushort_t*)(ws + (8u << 20));               // 4 MB  [b,h,d,n]
    ushort_t* xb = (ushort_t*)(ws + (12u << 20));              // 4 MB  x in bf16
    ushort_t* wt = (ushort_t*)(ws + (16u << 20));              // 1.5 MB w_qkv^T bf16
    ushort_t* wot = (ushort_t*)(ws + (16u << 20) + 1572864u);  // 0.5 MB w_out^T bf16
    float* out = (float*)d_out;

    k_cvt<<<dim3(2048), dim3(256), 0, stream>>>((const floatx4*)x, (short4v*)xb, 524288);
    k_transpose_cvt<<<dim3(48, 16), dim3(256), 0, stream>>>(w_qkv, wt, 512, 1536);
    k_transpose_cvt<<<dim3(16, 16), dim3(256), 0, stream>>>(w_out, wot, 512, 512);
    k_qkv<<<dim3(24, 32), dim3(256), 0, stream>>>(xb, wt, qs, ks, vt);
    k_attn<<<dim3(128, 2), dim3(256), 0, stream>>>(qs, ks, vt, w_pre, w_post, wot, b_out, out);
}